// Round 13
// baseline (110.128 us; speedup 1.0000x reference)
//
#include <hip/hip_runtime.h>

#define R_MAX 32
#define DIM_OUT 128
#define N_R 66              // 2*R_MAX + 2
#define DIM_IN 139          // 2*N_R + 1 + N_S
#define IROWS_PER_BLOCK 4   // 4 x 512 KB = 2 MB contiguous stream per block

typedef float f32x4 __attribute__((ext_vector_type(4)));

// out[bi, i, j, d] = W[d, N_R + clip(i-j+32,0,64)] + (W[d,32] + W[d,132] + W[d,138])
// ~94% of (i,j) saturate the bucket -> two per-thread constant float4s.
// R12 lesson: band source (LDS vs global) is NOT the bottleneck. New theory:
// 2048 concurrent 256KB write streams degrade DRAM page locality; the 6.8 TB/s
// fillBuffer reference uses ~215 blocks with ~10MB streams. Match that shape:
// 256 blocks, one per CU, each streaming 2MB contiguous with x4-unrolled stores.
__global__ __launch_bounds__(256) void rpe_kernel(const int* __restrict__ p_seq,
                                                  const float* __restrict__ W,
                                                  f32x4* __restrict__ out,
                                                  unsigned long long n_rows) {
    const unsigned seq = (unsigned)*p_seq;
    const unsigned tid = threadIdx.x;
    const unsigned lane = tid & 31;          // column group: floats [lane*4, lane*4+4)
    const float* w0 = W + (size_t)(lane * 4) * DIM_IN;

    // Per-thread constants (exact reference association order).
    float cst[4];
    f32x4 vhi, vlo;
    #pragma unroll
    for (int k = 0; k < 4; ++k) {
        const float* w = w0 + (size_t)k * DIM_IN;
        cst[k] = (w[R_MAX] + w[2 * N_R]) + w[DIM_IN - 1];
        vhi[k] = w[N_R + 2 * R_MAX] + cst[k];   // bucket 64 (j <= i-32)
        vlo[k] = w[N_R + 0] + cst[k];           // bucket 0  (j >= i+32)
    }

    const unsigned n_irows = (unsigned)(n_rows / seq);  // batch * seq
    const unsigned n_groups = (n_irows + IROWS_PER_BLOCK - 1) / IROWS_PER_BLOCK;

    for (unsigned g = blockIdx.x; g < n_groups; g += gridDim.x) {
        const unsigned r_end = min((g + 1) * IROWS_PER_BLOCK, n_irows);
        for (unsigned irow = g * IROWS_PER_BLOCK; irow < r_end; ++irow) {
            const int i = (int)(irow % seq);

            // j < i-31 -> vhi; j in [i-31, i+31] -> band; j >= i+32 -> vlo
            int e1 = i - 31; e1 = e1 < 0 ? 0 : (e1 > (int)seq ? (int)seq : e1);
            int e2 = i + 32; e2 = e2 < 0 ? 0 : (e2 > (int)seq ? (int)seq : e2);

            f32x4* __restrict__ base = out + (size_t)irow * seq * (DIM_OUT / 4);

            // region 1: vhi stream, unrolled x4
            int f = (int)tid, end = e1 * 32;
            for (; f + 768 < end; f += 1024) {
                __builtin_nontemporal_store(vhi, base + f);
                __builtin_nontemporal_store(vhi, base + f + 256);
                __builtin_nontemporal_store(vhi, base + f + 512);
                __builtin_nontemporal_store(vhi, base + f + 768);
            }
            for (; f < end; f += 256)
                __builtin_nontemporal_store(vhi, base + f);

            // region 2: 65-wide band, direct W gather (L1-resident after first row)
            f = e1 * 32 + (int)tid; end = e2 * 32;
            for (; f < end; f += 256) {
                const int j = f >> 5;
                const int b = i - j + R_MAX;            // in [1, 63]
                f32x4 v;
                v[0] = w0[0 * DIM_IN + N_R + b] + cst[0];
                v[1] = w0[1 * DIM_IN + N_R + b] + cst[1];
                v[2] = w0[2 * DIM_IN + N_R + b] + cst[2];
                v[3] = w0[3 * DIM_IN + N_R + b] + cst[3];
                __builtin_nontemporal_store(v, base + f);
            }

            // region 3: vlo stream, unrolled x4
            f = e2 * 32 + (int)tid; end = (int)seq * 32;
            for (; f + 768 < end; f += 1024) {
                __builtin_nontemporal_store(vlo, base + f);
                __builtin_nontemporal_store(vlo, base + f + 256);
                __builtin_nontemporal_store(vlo, base + f + 512);
                __builtin_nontemporal_store(vlo, base + f + 768);
            }
            for (; f < end; f += 256)
                __builtin_nontemporal_store(vlo, base + f);
        }
    }
}

extern "C" void kernel_launch(void* const* d_in, const int* in_sizes, int n_in,
                              void* d_out, int out_size, void* d_ws, size_t ws_size,
                              hipStream_t stream) {
    // Inputs per setup_inputs() order: batch_size (int), seq_len (int), W (float32)
    const int* p_seq = (const int*)d_in[1];
    const float* W = (const float*)d_in[2];
    f32x4* out = (f32x4*)d_out;

    const unsigned long long n_rows = (unsigned long long)out_size / DIM_OUT;

    // 256 blocks = 1/CU, each streams IROWS_PER_BLOCK contiguous rows (2 MB at
    // seq=1024) — mimics fillBufferAligned's few-blocks/long-streams shape.
    rpe_kernel<<<256, 256, 0, stream>>>(p_seq, W, out, n_rows);
}

// Round 14
// 102.443 us; speedup vs baseline: 1.0750x; 1.0750x over previous
//
#include <hip/hip_runtime.h>

#define R_MAX 32
#define DIM_OUT 128
#define N_R 66              // 2*R_MAX + 2
#define DIM_IN 139          // 2*N_R + 1 + N_S

typedef float f32x4 __attribute__((ext_vector_type(4)));

// out[bi, i, j, d] = W[d, N_R + clip(i-j+32,0,64)] + (W[d,32] + W[d,132] + W[d,138])
// ~94% of (i,j) saturate the bucket -> two per-thread constant float4s.
// R13 A/B: same structure as the 105.8us R11 kernel but with PLAIN stores
// (no nontemporal flag). R11/R12/R13 all used nt and all tied at ~5 TB/s while
// plain-store fillBuffer hits 6.7-6.8 TB/s on the same runs — nt's L2
// bypass/eviction policy is the last untested difference vs the fill shape.
__global__ __launch_bounds__(256) void rpe_kernel(const int* __restrict__ p_seq,
                                                  const float* __restrict__ W,
                                                  f32x4* __restrict__ out,
                                                  unsigned long long n_rows) {
    const unsigned seq = (unsigned)*p_seq;
    const unsigned tid = threadIdx.x;
    const unsigned lane = tid & 31;          // column group: floats [lane*4, lane*4+4)
    const float* w0 = W + (size_t)(lane * 4) * DIM_IN;

    // Per-thread constants (exact reference association order).
    float cst[4];
    f32x4 vhi, vlo;
    #pragma unroll
    for (int k = 0; k < 4; ++k) {
        const float* w = w0 + (size_t)k * DIM_IN;
        cst[k] = (w[R_MAX] + w[2 * N_R]) + w[DIM_IN - 1];
        vhi[k] = w[N_R + 2 * R_MAX] + cst[k];   // bucket 64 (j <= i-32)
        vlo[k] = w[N_R + 0] + cst[k];           // bucket 0  (j >= i+32)
    }

    const unsigned n_irows = (unsigned)(n_rows / seq);  // batch * seq
    const unsigned CPR = 2;                              // chunks per i-row
    const unsigned total_chunks = n_irows * CPR;

    for (unsigned chunk = blockIdx.x; chunk < total_chunks; chunk += gridDim.x) {
        const unsigned irow = chunk / CPR;
        const unsigned half = chunk - irow * CPR;
        const int i = (int)(irow % seq);
        const int j0 = (int)((half * seq) / CPR);
        const int j1 = (int)(((half + 1) * seq) / CPR);

        // j < i-31 -> vhi; j in [i-31, i+31] -> band; j >= i+32 -> vlo
        int e1 = i - 31; e1 = e1 < j0 ? j0 : (e1 > j1 ? j1 : e1);
        int e2 = i + 32; e2 = e2 < j0 ? j0 : (e2 > j1 ? j1 : e2);

        f32x4* __restrict__ base = out + (size_t)irow * seq * (DIM_OUT / 4);

        // region 1: pure store stream of vhi
        for (int f = j0 * 32 + (int)tid; f < e1 * 32; f += 256)
            base[f] = vhi;

        // region 2: 65-wide band, direct W gather (L1/L2-resident)
        for (int f = e1 * 32 + (int)tid; f < e2 * 32; f += 256) {
            const int j = f >> 5;
            const int b = i - j + R_MAX;            // in [1, 63]
            f32x4 v;
            v[0] = w0[0 * DIM_IN + N_R + b] + cst[0];
            v[1] = w0[1 * DIM_IN + N_R + b] + cst[1];
            v[2] = w0[2 * DIM_IN + N_R + b] + cst[2];
            v[3] = w0[3 * DIM_IN + N_R + b] + cst[3];
            base[f] = v;
        }

        // region 3: pure store stream of vlo
        for (int f = e2 * 32 + (int)tid; f < j1 * 32; f += 256)
            base[f] = vlo;
    }
}

extern "C" void kernel_launch(void* const* d_in, const int* in_sizes, int n_in,
                              void* d_out, int out_size, void* d_ws, size_t ws_size,
                              hipStream_t stream) {
    // Inputs per setup_inputs() order: batch_size (int), seq_len (int), W (float32)
    const int* p_seq = (const int*)d_in[1];
    const float* W = (const float*)d_in[2];
    f32x4* out = (f32x4*)d_out;

    const unsigned long long n_rows = (unsigned long long)out_size / DIM_OUT;

    // 2048 blocks: for seq=1024, one 256 KB chunk per block (R11 shape).
    rpe_kernel<<<2048, 256, 0, stream>>>(p_seq, W, out, n_rows);
}